// Round 1
// baseline (1334.684 us; speedup 1.0000x reference)
//
#include <hip/hip_runtime.h>
#include <cstdint>

#define NV 3
#define NN 4096
#define HH 256
#define CC 20
#define DYY 300
#define DD 512

// ---------------------------------------------------------------- k_yn
// y_n[c][h] = sigmoid(y[c] . Wy[h] + by[h])   (C=20 blocks x 256 thr)
__global__ __launch_bounds__(256) void k_yn(
    const float* __restrict__ y, const float* __restrict__ Wy,
    const float* __restrict__ by, float* __restrict__ YN)
{
    __shared__ float ysh[DYY];
    int c = blockIdx.x, tid = threadIdx.x;
    for (int i = tid; i < DYY; i += 256) ysh[i] = y[c * DYY + i];
    __syncthreads();
    float acc = by[tid];
    const float* Wr = Wy + (size_t)tid * DYY;
    for (int d = 0; d < DYY; ++d) acc += ysh[d] * Wr[d];
    YN[c * HH + tid] = 1.0f / (1.0f + __expf(-acc));
}

// ---------------------------------------------------------------- k_proj
// xp = leaky(x@W^T + b); xq = xp/||xp||; xpm = xp * mt[v][n]
// 8 rows per block, one v per block.  grid = V*N/8
__global__ __launch_bounds__(256) void k_proj(
    const float* __restrict__ x0, const float* __restrict__ x1, const float* __restrict__ x2,
    const float* __restrict__ W0, const float* __restrict__ W1, const float* __restrict__ W2,
    const float* __restrict__ b0, const float* __restrict__ b1, const float* __restrict__ b2,
    const int* __restrict__ mask,
    float* __restrict__ XP, float* __restrict__ XQ, float* __restrict__ XPM)
{
    const int R = 8;
    int tid = threadIdx.x;
    int blk = blockIdx.x;
    int v  = blk / (NN / R);
    int n0 = (blk % (NN / R)) * R;
    const float* xv = (v == 0) ? x0 : (v == 1 ? x1 : x2);
    const float* Wv = (v == 0) ? W0 : (v == 1 ? W1 : W2);
    const float* bv = (v == 0) ? b0 : (v == 1 ? b1 : b2);

    __shared__ __align__(16) float xsh[R][DD];   // 16 KB
    __shared__ float wred[4][R];
    __shared__ float nrm_sh[R];
    __shared__ int   msk_sh[R];

    const float4* xsrc = (const float4*)(xv + (size_t)n0 * DD);
    for (int i = tid; i < R * DD / 4; i += 256)
        ((float4*)xsh)[i] = xsrc[i];
    if (tid < R) msk_sh[tid] = mask[(n0 + tid) * NV + v];
    __syncthreads();

    float acc[R];
#pragma unroll
    for (int r = 0; r < R; ++r) acc[r] = 0.0f;
    const float4* Wrow = (const float4*)(Wv + (size_t)tid * DD);
    for (int d4 = 0; d4 < DD / 4; ++d4) {
        float4 w = Wrow[d4];
#pragma unroll
        for (int r = 0; r < R; ++r) {
            acc[r] = fmaf(xsh[r][4 * d4 + 0], w.x, acc[r]);
            acc[r] = fmaf(xsh[r][4 * d4 + 1], w.y, acc[r]);
            acc[r] = fmaf(xsh[r][4 * d4 + 2], w.z, acc[r]);
            acc[r] = fmaf(xsh[r][4 * d4 + 3], w.w, acc[r]);
        }
    }
    float bb = bv[tid];
    float vals[R];
#pragma unroll
    for (int r = 0; r < R; ++r) {
        float t = acc[r] + bb;
        vals[r] = (t >= 0.0f) ? t : 0.1f * t;   // leaky, slope 0.1
    }
    int lane = tid & 63, wv = tid >> 6;
#pragma unroll
    for (int r = 0; r < R; ++r) {
        float sq = vals[r] * vals[r];
#pragma unroll
        for (int off = 32; off > 0; off >>= 1)
            sq += __shfl_down(sq, off, 64);
        if (lane == 0) wred[wv][r] = sq;
    }
    __syncthreads();
    if (tid < R) {
        float s = wred[0][tid] + wred[1][tid] + wred[2][tid] + wred[3][tid];
        nrm_sh[tid] = fmaxf(sqrtf(s), 1e-12f);
    }
    __syncthreads();
#pragma unroll
    for (int r = 0; r < R; ++r) {
        size_t o = ((size_t)v * NN + n0 + r) * HH + tid;
        float xpv = vals[r];
        XP[o]  = xpv;
        XQ[o]  = xpv / nrm_sh[r];
        XPM[o] = msk_sh[r] ? xpv : 0.0f;
    }
}

// ---------------------------------------------------------------- k_scores
// S[n][m] = (n!=m) ? max_v( mn*mm * exp(5*dot(xq_vn,xq_vm)) ) : 0
// 64x64 tile per block; K-chunks of 32, k-major LDS for b128 reads.
__global__ __launch_bounds__(256) void k_scores(
    const float* __restrict__ XQ, const int* __restrict__ mask, float* __restrict__ S)
{
    int m0 = blockIdx.x * 64;
    int n0 = blockIdx.y * 64;
    int tid = threadIdx.x;
    int tr = tid >> 4;      // 0..15 -> rows tr*4..+3
    int tc = tid & 15;      // 0..15 -> cols tc*4..+3

    __shared__ __align__(16) float Aq[NV][32][68];
    __shared__ __align__(16) float Bq[NV][32][68];
    __shared__ int mn[NV][64], mm[NV][64];

    if (tid < 64) {
#pragma unroll
        for (int v = 0; v < NV; ++v) {
            mn[v][tid] = mask[(n0 + tid) * NV + v];
            mm[v][tid] = mask[(m0 + tid) * NV + v];
        }
    }

    float acc[NV][4][4];
#pragma unroll
    for (int v = 0; v < NV; ++v)
#pragma unroll
        for (int i = 0; i < 4; ++i)
#pragma unroll
            for (int j = 0; j < 4; ++j) acc[v][i][j] = 0.0f;

    for (int kc0 = 0; kc0 < HH; kc0 += 32) {
        __syncthreads();
        // stage: global (row-major, coalesced float4) -> LDS (k-major)
        for (int i = tid; i < NV * 64 * 8; i += 256) {
            int v = i >> 9; int rem = i & 511; int row = rem >> 3; int k4 = rem & 7;
            float4 qa = *(const float4*)&XQ[((size_t)v * NN + n0 + row) * HH + kc0 + k4 * 4];
            float4 qb = *(const float4*)&XQ[((size_t)v * NN + m0 + row) * HH + kc0 + k4 * 4];
            Aq[v][k4 * 4 + 0][row] = qa.x; Aq[v][k4 * 4 + 1][row] = qa.y;
            Aq[v][k4 * 4 + 2][row] = qa.z; Aq[v][k4 * 4 + 3][row] = qa.w;
            Bq[v][k4 * 4 + 0][row] = qb.x; Bq[v][k4 * 4 + 1][row] = qb.y;
            Bq[v][k4 * 4 + 2][row] = qb.z; Bq[v][k4 * 4 + 3][row] = qb.w;
        }
        __syncthreads();
#pragma unroll 8
        for (int kk = 0; kk < 32; ++kk) {
#pragma unroll
            for (int v = 0; v < NV; ++v) {
                float4 av = *(const float4*)&Aq[v][kk][tr * 4];
                float4 bv = *(const float4*)&Bq[v][kk][tc * 4];
                float a4[4] = {av.x, av.y, av.z, av.w};
                float b4[4] = {bv.x, bv.y, bv.z, bv.w};
#pragma unroll
                for (int i = 0; i < 4; ++i)
#pragma unroll
                    for (int j = 0; j < 4; ++j)
                        acc[v][i][j] = fmaf(a4[i], b4[j], acc[v][i][j]);
            }
        }
    }
    __syncthreads();
#pragma unroll
    for (int i = 0; i < 4; ++i) {
        int n = n0 + tr * 4 + i;
        float4 o;
        float* op = &o.x;
#pragma unroll
        for (int j = 0; j < 4; ++j) {
            int m = m0 + tc * 4 + j;
            float s = 0.0f;
#pragma unroll
            for (int v = 0; v < NV; ++v) {
                if (mn[v][tr * 4 + i] && mm[v][tc * 4 + j])
                    s = fmaxf(s, __expf(acc[v][i][j] * 5.0f));
            }
            if (n == m) s = 0.0f;
            op[j] = s;
        }
        *(float4*)&S[(size_t)n * NN + m0 + tc * 4] = o;
    }
}

// ---------------------------------------------------------------- k_rowstats
// RS[n] = sum_m S[n][m];  CONF[v][n] = clip(max_m (mt[v][m] ? 0.2*log(S+1e-9) : 0), 0, 1)
__global__ __launch_bounds__(256) void k_rowstats(
    const float* __restrict__ S, const int* __restrict__ mask,
    float* __restrict__ RS, float* __restrict__ CONF)
{
    int n = blockIdx.x, tid = threadIdx.x;
    float lsum = 0.0f;
    float lm[NV] = {-1e30f, -1e30f, -1e30f};
    const float* Srow = S + (size_t)n * NN;
    for (int m = tid; m < NN; m += 256) {
        float sv = Srow[m];
        lsum += sv;
        float lg = 0.2f * logf(sv + 1e-9f);
        int mb = m * NV;
#pragma unroll
        for (int v = 0; v < NV; ++v) {
            float term = mask[mb + v] ? lg : 0.0f;
            lm[v] = fmaxf(lm[v], term);
        }
    }
    int lane = tid & 63, wv = tid >> 6;
    __shared__ float ssum[4];
    __shared__ float smax[4][NV];
#pragma unroll
    for (int off = 32; off > 0; off >>= 1) {
        lsum += __shfl_down(lsum, off, 64);
#pragma unroll
        for (int v = 0; v < NV; ++v)
            lm[v] = fmaxf(lm[v], __shfl_down(lm[v], off, 64));
    }
    if (lane == 0) {
        ssum[wv] = lsum;
#pragma unroll
        for (int v = 0; v < NV; ++v) smax[wv][v] = lm[v];
    }
    __syncthreads();
    if (tid == 0) RS[n] = ssum[0] + ssum[1] + ssum[2] + ssum[3];
    if (tid < NV) {
        float cm = fmaxf(fmaxf(smax[0][tid], smax[1][tid]),
                         fmaxf(smax[2][tid], smax[3][tid]));
        CONF[tid * NN + n] = fminf(fmaxf(cm, 0.0f), 1.0f);
    }
}

// ---------------------------------------------------------------- k_newx
// NX[v][n][h] = mt[v][n] ? xp[v][n][h]
//                        : (sum_m S[n][m]*xpm[v][m][h]) / (RS[n]+1e-9)
// 32n x 64h tile per block; all 3 v per block.  grid = (N/32, H/64)
__global__ __launch_bounds__(256) void k_newx(
    const float* __restrict__ S, const float* __restrict__ XP,
    const float* __restrict__ XPM, const float* __restrict__ RS,
    const int* __restrict__ mask, float* __restrict__ NX)
{
    int n0 = blockIdx.x * 32;
    int h0 = blockIdx.y * 64;
    int tid = threadIdx.x;
    int tr = tid >> 4;      // 0..15 -> rows tr*2..+1
    int tc = tid & 15;      // cols tc*4..+3

    __shared__ __align__(16) float St[32][34];        // [k][row]
    __shared__ __align__(16) float Xt[NV][32][64];    // [v][k][h]
    __shared__ float rsn[32];
    __shared__ int   mnn[NV][32];

    if (tid < 32) {
        rsn[tid] = RS[n0 + tid] + 1e-9f;
#pragma unroll
        for (int v = 0; v < NV; ++v)
            mnn[v][tid] = mask[(n0 + tid) * NV + v];
    }

    float acc[NV][2][4];
#pragma unroll
    for (int v = 0; v < NV; ++v)
#pragma unroll
        for (int i = 0; i < 2; ++i)
#pragma unroll
            for (int j = 0; j < 4; ++j) acc[v][i][j] = 0.0f;

    for (int mm0 = 0; mm0 < NN; mm0 += 32) {
        __syncthreads();
        {   // S tile: 32 rows x 32 k  (one float4 per thread)
            int r = tid >> 3, k4 = tid & 7;
            float4 sv = *(const float4*)&S[(size_t)(n0 + r) * NN + mm0 + k4 * 4];
            St[k4 * 4 + 0][r] = sv.x; St[k4 * 4 + 1][r] = sv.y;
            St[k4 * 4 + 2][r] = sv.z; St[k4 * 4 + 3][r] = sv.w;
        }
        for (int i = tid; i < NV * 32 * 16; i += 256) {
            int v = i >> 9; int rem = i & 511; int mk = rem >> 4; int h4 = rem & 15;
            float4 xv = *(const float4*)&XPM[((size_t)v * NN + mm0 + mk) * HH + h0 + h4 * 4];
            *(float4*)&Xt[v][mk][h4 * 4] = xv;
        }
        __syncthreads();
#pragma unroll 8
        for (int kk = 0; kk < 32; ++kk) {
            float sa0 = St[kk][tr * 2 + 0];
            float sa1 = St[kk][tr * 2 + 1];
#pragma unroll
            for (int v = 0; v < NV; ++v) {
                float4 xb = *(const float4*)&Xt[v][kk][tc * 4];
                float b4[4] = {xb.x, xb.y, xb.z, xb.w};
#pragma unroll
                for (int j = 0; j < 4; ++j) {
                    acc[v][0][j] = fmaf(sa0, b4[j], acc[v][0][j]);
                    acc[v][1][j] = fmaf(sa1, b4[j], acc[v][1][j]);
                }
            }
        }
    }
    __syncthreads();
#pragma unroll
    for (int v = 0; v < NV; ++v)
#pragma unroll
        for (int i = 0; i < 2; ++i) {
            int nr = tr * 2 + i;
            int n  = n0 + nr;
            size_t o = ((size_t)v * NN + n) * HH + h0 + tc * 4;
            float4 ov;
            if (mnn[v][nr]) {
                ov = *(const float4*)&XP[o];
            } else {
                float d = rsn[nr];
                ov.x = acc[v][i][0] / d; ov.y = acc[v][i][1] / d;
                ov.z = acc[v][i][2] / d; ov.w = acc[v][i][3] / d;
            }
            *(float4*)&NX[o] = ov;
        }
}

// ---------------------------------------------------------------- k_z
// Z[v][n][c][h] = NX[v][n][h] * YN[c][h]   (grid = V*N blocks)
__global__ __launch_bounds__(256) void k_z(
    const float* __restrict__ NX, const float* __restrict__ YN,
    float* __restrict__ Z)
{
    int blk = blockIdx.x;   // v*N + n
    int tid = threadIdx.x;
    float nx = NX[(size_t)blk * HH + tid];
    size_t base = (size_t)blk * CC * HH;
#pragma unroll
    for (int c = 0; c < CC; ++c)
        Z[base + (size_t)c * HH + tid] = nx * YN[c * HH + tid];
}

// ---------------------------------------------------------------- launch
extern "C" void kernel_launch(void* const* d_in, const int* in_sizes, int n_in,
                              void* d_out, int out_size, void* d_ws, size_t ws_size,
                              hipStream_t stream)
{
    (void)in_sizes; (void)n_in; (void)out_size; (void)ws_size;
    const float* x0 = (const float*)d_in[0];
    const float* W0 = (const float*)d_in[1];
    const float* b0 = (const float*)d_in[2];
    const float* x1 = (const float*)d_in[3];
    const float* W1 = (const float*)d_in[4];
    const float* b1 = (const float*)d_in[5];
    const float* x2 = (const float*)d_in[6];
    const float* W2 = (const float*)d_in[7];
    const float* b2 = (const float*)d_in[8];
    const float* y  = (const float*)d_in[9];
    const float* Wy = (const float*)d_in[10];
    const float* by = (const float*)d_in[11];
    const int* mask = (const int*)d_in[12];
    float* out = (float*)d_out;

    // Scratch carved out of d_out's Z region (all dead before k_z writes Z):
    //   S:   N*N            = 16,777,216 f32
    //   XP:  V*N*H          =  3,145,728 f32
    //   XQ:  V*N*H
    //   XPM: V*N*H          -> total 26,214,400 f32 < 62,914,560 (Z region)
    float* S    = out;
    float* XP   = out + (size_t)NN * NN;
    float* XQ   = XP  + (size_t)NV * NN * HH;
    float* XPM  = XQ  + (size_t)NV * NN * HH;
    float* CONF = out + (size_t)NV * NN * CC * HH;   // final confi output

    // ws: NX (V*N*H) + RS (N) + YN (C*H)  ~= 12.6 MB
    float* NX = (float*)d_ws;
    float* RS = NX + (size_t)NV * NN * HH;
    float* YN = RS + NN;

    k_yn<<<CC, 256, 0, stream>>>(y, Wy, by, YN);
    k_proj<<<NV * NN / 8, 256, 0, stream>>>(x0, x1, x2, W0, W1, W2,
                                            b0, b1, b2, mask, XP, XQ, XPM);
    dim3 gs(NN / 64, NN / 64);
    k_scores<<<gs, 256, 0, stream>>>(XQ, mask, S);
    k_rowstats<<<NN, 256, 0, stream>>>(S, mask, RS, CONF);
    dim3 gn(NN / 32, HH / 64);
    k_newx<<<gn, 256, 0, stream>>>(S, XP, XPM, RS, mask, NX);
    k_z<<<NV * NN, 256, 0, stream>>>(NX, YN, out);
}

// Round 2
// 766.862 us; speedup vs baseline: 1.7404x; 1.7404x over previous
//
#include <hip/hip_runtime.h>
#include <hip/hip_bf16.h>
#include <cstdint>

#define NV 3
#define NN 4096
#define HH 256
#define CC 20
#define DYY 300
#define DD 512

typedef __bf16 v8bf  __attribute__((ext_vector_type(8)));
typedef float  v16f  __attribute__((ext_vector_type(16)));

static __device__ __forceinline__ float bf2f(unsigned short u) {
    union { unsigned int i; float f; } c; c.i = ((unsigned int)u) << 16; return c.f;
}

// ---------------------------------------------------------------- k_yn
// y_n[c][h] = sigmoid(y[c] . Wy[h] + by[h])
__global__ __launch_bounds__(256) void k_yn(
    const float* __restrict__ y, const float* __restrict__ Wy,
    const float* __restrict__ by, float* __restrict__ YN)
{
    __shared__ float ysh[DYY];
    int c = blockIdx.x, tid = threadIdx.x;
    for (int i = tid; i < DYY; i += 256) ysh[i] = y[c * DYY + i];
    __syncthreads();
    float acc = by[tid];
    const float* Wr = Wy + (size_t)tid * DYY;
    for (int d = 0; d < DYY; ++d) acc += ysh[d] * Wr[d];
    YN[c * HH + tid] = 1.0f / (1.0f + __expf(-acc));
}

// ---------------------------------------------------------------- k_proj
// xp = leaky(x@W^T + b); outputs:
//   XP   f32  [v][n][h]   (epilogue passthrough for masked rows)
//   XQh  bf16 [v][n][h]   (normalized rows; MFMA A/B for k_scores)
//   XPMT bf16 [v][h][n]   (masked xp, TRANSPOSED; MFMA B for k_newx)
__global__ __launch_bounds__(256) void k_proj(
    const float* __restrict__ x0, const float* __restrict__ x1, const float* __restrict__ x2,
    const float* __restrict__ W0, const float* __restrict__ W1, const float* __restrict__ W2,
    const float* __restrict__ b0, const float* __restrict__ b1, const float* __restrict__ b2,
    const int* __restrict__ mask,
    float* __restrict__ XP, __hip_bfloat16* __restrict__ XQh,
    __hip_bfloat16* __restrict__ XPMT)
{
    const int R = 8;
    int tid = threadIdx.x;
    int blk = blockIdx.x;
    int v  = blk / (NN / R);
    int n0 = (blk % (NN / R)) * R;
    const float* xv = (v == 0) ? x0 : (v == 1 ? x1 : x2);
    const float* Wv = (v == 0) ? W0 : (v == 1 ? W1 : W2);
    const float* bv = (v == 0) ? b0 : (v == 1 ? b1 : b2);

    __shared__ __align__(16) float xsh[R][DD];
    __shared__ float wred[4][R];
    __shared__ float nrm_sh[R];
    __shared__ int   msk_sh[R];

    const float4* xsrc = (const float4*)(xv + (size_t)n0 * DD);
    for (int i = tid; i < R * DD / 4; i += 256)
        ((float4*)xsh)[i] = xsrc[i];
    if (tid < R) msk_sh[tid] = mask[(n0 + tid) * NV + v];
    __syncthreads();

    float acc[R];
#pragma unroll
    for (int r = 0; r < R; ++r) acc[r] = 0.0f;
    const float4* Wrow = (const float4*)(Wv + (size_t)tid * DD);
    for (int d4 = 0; d4 < DD / 4; ++d4) {
        float4 w = Wrow[d4];
#pragma unroll
        for (int r = 0; r < R; ++r) {
            acc[r] = fmaf(xsh[r][4 * d4 + 0], w.x, acc[r]);
            acc[r] = fmaf(xsh[r][4 * d4 + 1], w.y, acc[r]);
            acc[r] = fmaf(xsh[r][4 * d4 + 2], w.z, acc[r]);
            acc[r] = fmaf(xsh[r][4 * d4 + 3], w.w, acc[r]);
        }
    }
    float bb = bv[tid];
    float vals[R];
#pragma unroll
    for (int r = 0; r < R; ++r) {
        float t = acc[r] + bb;
        vals[r] = (t >= 0.0f) ? t : 0.1f * t;
    }
    int lane = tid & 63, wv = tid >> 6;
#pragma unroll
    for (int r = 0; r < R; ++r) {
        float sq = vals[r] * vals[r];
#pragma unroll
        for (int off = 32; off > 0; off >>= 1)
            sq += __shfl_down(sq, off, 64);
        if (lane == 0) wred[wv][r] = sq;
    }
    __syncthreads();
    if (tid < R) {
        float s = wred[0][tid] + wred[1][tid] + wred[2][tid] + wred[3][tid];
        nrm_sh[tid] = fmaxf(sqrtf(s), 1e-12f);
    }
    __syncthreads();
    union { __hip_bfloat16 h[8]; uint4 u; } pk;
#pragma unroll
    for (int r = 0; r < R; ++r) {
        size_t o = ((size_t)v * NN + n0 + r) * HH + tid;
        float xpv = vals[r];
        XP[o]  = xpv;
        XQh[o] = __float2bfloat16(xpv / nrm_sh[r]);
        pk.h[r] = __float2bfloat16(msk_sh[r] ? xpv : 0.0f);
    }
    *(uint4*)&XPMT[((size_t)v * HH + tid) * NN + n0] = pk.u;
}

// ---------------------------------------------------------------- k_scores
// S[n][m] = (n!=m) ? max_v( mn*mm * exp(5*dot(xq_vn,xq_vm)) ) : 0   (bf16 out)
// 64x64 tile / block; 4 waves, each one 32x32 MFMA tile with 3 v-accumulators.
__global__ __launch_bounds__(256) void k_scores(
    const __hip_bfloat16* __restrict__ XQh, const int* __restrict__ mask,
    __hip_bfloat16* __restrict__ Sb)
{
    int m0 = blockIdx.x * 64, n0 = blockIdx.y * 64;
    int tid = threadIdx.x, lane = tid & 63, wid = tid >> 6;
    int wr = (wid >> 1) * 32, wc = (wid & 1) * 32;

    __shared__ int mn[NV][64], mm[NV][64];
    if (tid < 64) {
#pragma unroll
        for (int v = 0; v < NV; ++v) {
            mn[v][tid] = mask[(n0 + tid) * NV + v];
            mm[v][tid] = mask[(m0 + tid) * NV + v];
        }
    }
    __syncthreads();

    v16f acc[NV];
#pragma unroll
    for (int v = 0; v < NV; ++v) acc[v] = (v16f)0.0f;

    const __bf16* Q = (const __bf16*)XQh;
    const __bf16* Ap = Q + (size_t)(n0 + wr + (lane & 31)) * HH + ((lane >> 5) * 8);
    const __bf16* Bp = Q + (size_t)(m0 + wc + (lane & 31)) * HH + ((lane >> 5) * 8);

#pragma unroll 2
    for (int k0 = 0; k0 < HH; k0 += 16) {
#pragma unroll
        for (int v = 0; v < NV; ++v) {
            v8bf a = *(const v8bf*)(Ap + (size_t)v * NN * HH + k0);
            v8bf b = *(const v8bf*)(Bp + (size_t)v * NN * HH + k0);
            acc[v] = __builtin_amdgcn_mfma_f32_32x32x16_bf16(a, b, acc[v], 0, 0, 0);
        }
    }

    int col = lane & 31, m = m0 + wc + col;
#pragma unroll
    for (int reg = 0; reg < 16; ++reg) {
        int row = (reg & 3) + 8 * (reg >> 2) + 4 * (lane >> 5);
        int nr = wr + row, n = n0 + nr;
        float s = 0.0f;
#pragma unroll
        for (int v = 0; v < NV; ++v) {
            if (mn[v][nr] && mm[v][wc + col])
                s = fmaxf(s, __expf(acc[v][reg] * 5.0f));
        }
        if (n == m) s = 0.0f;
        Sb[(size_t)n * NN + m] = __float2bfloat16(s);
    }
}

// ---------------------------------------------------------------- k_rowstats
// RS[n] = sum_m S[n][m];  CONF[v][n] = clip(max_m (mt[v][m] ? 0.2*log(S+1e-9) : 0), 0, 1)
__global__ __launch_bounds__(256) void k_rowstats(
    const __hip_bfloat16* __restrict__ Sb, const int* __restrict__ mask,
    float* __restrict__ RS, float* __restrict__ CONF)
{
    int n = blockIdx.x, tid = threadIdx.x;
    float lsum = 0.0f;
    float lm[NV] = {-1e30f, -1e30f, -1e30f};
    const ushort4* S4 = (const ushort4*)(Sb + (size_t)n * NN);
    for (int i = tid; i < NN / 4; i += 256) {
        ushort4 u = S4[i];
        float f[4] = {bf2f(u.x), bf2f(u.y), bf2f(u.z), bf2f(u.w)};
        int mbase = (i * 4) * NV;
#pragma unroll
        for (int j = 0; j < 4; ++j) {
            lsum += f[j];
            float lg = 0.2f * __logf(f[j] + 1e-9f);
#pragma unroll
            for (int v = 0; v < NV; ++v) {
                float term = mask[mbase + j * NV + v] ? lg : 0.0f;
                lm[v] = fmaxf(lm[v], term);
            }
        }
    }
    int lane = tid & 63, wv = tid >> 6;
    __shared__ float ssum[4];
    __shared__ float smax[4][NV];
#pragma unroll
    for (int off = 32; off > 0; off >>= 1) {
        lsum += __shfl_down(lsum, off, 64);
#pragma unroll
        for (int v = 0; v < NV; ++v)
            lm[v] = fmaxf(lm[v], __shfl_down(lm[v], off, 64));
    }
    if (lane == 0) {
        ssum[wv] = lsum;
#pragma unroll
        for (int v = 0; v < NV; ++v) smax[wv][v] = lm[v];
    }
    __syncthreads();
    if (tid == 0) RS[n] = ssum[0] + ssum[1] + ssum[2] + ssum[3];
    if (tid < NV) {
        float cm = fmaxf(fmaxf(smax[0][tid], smax[1][tid]),
                         fmaxf(smax[2][tid], smax[3][tid]));
        CONF[tid * NN + n] = fminf(fmaxf(cm, 0.0f), 1.0f);
    }
}

// ---------------------------------------------------------------- k_newx
// NX[v][n][h] = mt[v][n] ? xp : (S[n] . XPMT[v][h]) / (RS[n]+1e-9)
// grid (N/64, H/64, V); wave = one 32x32 MFMA tile, K=4096.
__global__ __launch_bounds__(256) void k_newx(
    const __hip_bfloat16* __restrict__ Sb, const __hip_bfloat16* __restrict__ XPMT,
    const float* __restrict__ XP, const float* __restrict__ RS,
    const int* __restrict__ mask, float* __restrict__ NX)
{
    int v  = blockIdx.z;
    int n0 = blockIdx.x * 64, h0 = blockIdx.y * 64;
    int tid = threadIdx.x, lane = tid & 63, wid = tid >> 6;
    int wr = (wid >> 1) * 32, wc = (wid & 1) * 32;

    __shared__ int   mn[64];
    __shared__ float rsn[64];
    if (tid < 64) {
        mn[tid]  = mask[(n0 + tid) * NV + v];
        rsn[tid] = 1.0f / (RS[n0 + tid] + 1e-9f);
    }
    __syncthreads();

    v16f acc = (v16f)0.0f;
    const __bf16* Ap = (const __bf16*)Sb + (size_t)(n0 + wr + (lane & 31)) * NN
                       + ((lane >> 5) * 8);
    const __bf16* Bp = (const __bf16*)XPMT + ((size_t)v * HH + h0 + wc + (lane & 31)) * NN
                       + ((lane >> 5) * 8);

#pragma unroll 4
    for (int k0 = 0; k0 < NN; k0 += 16) {
        v8bf a = *(const v8bf*)(Ap + k0);
        v8bf b = *(const v8bf*)(Bp + k0);
        acc = __builtin_amdgcn_mfma_f32_32x32x16_bf16(a, b, acc, 0, 0, 0);
    }

    int col = lane & 31, h = h0 + wc + col;
#pragma unroll
    for (int reg = 0; reg < 16; ++reg) {
        int row = (reg & 3) + 8 * (reg >> 2) + 4 * (lane >> 5);
        int nr = wr + row, n = n0 + nr;
        size_t o = ((size_t)v * NN + n) * HH + h;
        NX[o] = mn[nr] ? XP[o] : acc[reg] * rsn[nr];
    }
}

// ---------------------------------------------------------------- k_z
// Z[v][n][c][h] = NX[v][n][h] * YN[c][h]
__global__ __launch_bounds__(256) void k_z(
    const float* __restrict__ NX, const float* __restrict__ YN,
    float* __restrict__ Z)
{
    int blk = blockIdx.x;
    int tid = threadIdx.x;
    float nx = NX[(size_t)blk * HH + tid];
    size_t base = (size_t)blk * CC * HH;
#pragma unroll
    for (int c = 0; c < CC; ++c)
        Z[base + (size_t)c * HH + tid] = nx * YN[c * HH + tid];
}

// ---------------------------------------------------------------- launch
extern "C" void kernel_launch(void* const* d_in, const int* in_sizes, int n_in,
                              void* d_out, int out_size, void* d_ws, size_t ws_size,
                              hipStream_t stream)
{
    (void)in_sizes; (void)n_in; (void)out_size; (void)ws_size;
    const float* x0 = (const float*)d_in[0];
    const float* W0 = (const float*)d_in[1];
    const float* b0 = (const float*)d_in[2];
    const float* x1 = (const float*)d_in[3];
    const float* W1 = (const float*)d_in[4];
    const float* b1 = (const float*)d_in[5];
    const float* x2 = (const float*)d_in[6];
    const float* W2 = (const float*)d_in[7];
    const float* b2 = (const float*)d_in[8];
    const float* y  = (const float*)d_in[9];
    const float* Wy = (const float*)d_in[10];
    const float* by = (const float*)d_in[11];
    const int* mask = (const int*)d_in[12];
    float* out = (float*)d_out;

    // Scratch carved out of d_out's Z region (all dead before k_z writes Z):
    //   Sb   bf16 N*N        -> 8,388,608 f32-equiv
    //   XP   f32  V*N*H      -> 3,145,728
    //   XQh  bf16 V*N*H      -> 1,572,864 f32-equiv
    //   XPMT bf16 V*H*N      -> 1,572,864 f32-equiv
    //   total 14,680,064 f32 < 62,914,560 (Z region)
    __hip_bfloat16* Sb   = (__hip_bfloat16*)out;
    float*          XP   = out + 8388608;
    __hip_bfloat16* XQh  = (__hip_bfloat16*)(out + 11534336);
    __hip_bfloat16* XPMT = (__hip_bfloat16*)(out + 13107200);
    float*          CONF = out + (size_t)NV * NN * CC * HH;

    // ws: NX (V*N*H f32) + RS (N) + YN (C*H) ~= 12.6 MB
    float* NX = (float*)d_ws;
    float* RS = NX + (size_t)NV * NN * HH;
    float* YN = RS + NN;

    k_yn<<<CC, 256, 0, stream>>>(y, Wy, by, YN);
    k_proj<<<NV * NN / 8, 256, 0, stream>>>(x0, x1, x2, W0, W1, W2,
                                            b0, b1, b2, mask, XP, XQh, XPMT);
    dim3 gs(NN / 64, NN / 64);
    k_scores<<<gs, 256, 0, stream>>>(XQh, mask, Sb);
    k_rowstats<<<NN, 256, 0, stream>>>(Sb, mask, RS, CONF);
    dim3 gn(NN / 64, HH / 64, NV);
    k_newx<<<gn, 256, 0, stream>>>(Sb, XPMT, XP, RS, mask, NX);
    k_z<<<NV * NN, 256, 0, stream>>>(NX, YN, out);
}